// Round 11
// baseline (621.483 us; speedup 1.0000x reference)
//
#include <hip/hip_runtime.h>
#include <cstdint>
#include <cstddef>

// ---------------------------------------------------------------------------
// HierarchicalNetwork: 2-layer Bayesian transformer decoder + mixture heads.
// B=512 L=128 D=128 H=4 dk=32 DFF=256 T=2048
// RNG: JAX threefry2x32 partitionable, fold_in(key(42), c) c=0..45 (verified).
// R11 = R10 bugfix: R10 wrote 128-wide P rows into Ps[128][72] (overflow).
// Fix: hoist qa[4] frags to registers after Q-park; XbU is then dead during
// attention and serves as the full-width P buffer (wave-band-local, no new
// barriers). LN scratch gets its own small buffer. Col-partitioned GEMMs
// (W frags per-wave in registers from packed L2), row-partitioned attention.
// ---------------------------------------------------------------------------

#define NB   512
#define NL   128
#define ND   128
#define NH   4
#define NDFF 256
#define NT   2048
#define BL   (NB * NL)

typedef __attribute__((ext_vector_type(8))) short bf16x8;
typedef __attribute__((ext_vector_type(4))) float f32x4;

#define MFMA16(a, b, c) __builtin_amdgcn_mfma_f32_16x16x32_bf16((a), (b), (c), 0, 0, 0)

// ----------------------------- threefry2x32 --------------------------------
__host__ __device__ __forceinline__ void tf2x32(uint32_t k0, uint32_t k1,
                                                uint32_t x0, uint32_t x1,
                                                uint32_t& o0, uint32_t& o1)
{
  const uint32_t ks2 = k0 ^ k1 ^ 0x1BD11BDAu;
  x0 += k0; x1 += k1;
#define TF_RND(r) { x0 += x1; x1 = (x1 << (r)) | (x1 >> (32 - (r))); x1 ^= x0; }
  TF_RND(13) TF_RND(15) TF_RND(26) TF_RND(6)
  x0 += k1;  x1 += ks2 + 1u;
  TF_RND(17) TF_RND(29) TF_RND(16) TF_RND(24)
  x0 += ks2; x1 += k0 + 2u;
  TF_RND(13) TF_RND(15) TF_RND(26) TF_RND(6)
  x0 += k0;  x1 += k1 + 3u;
  TF_RND(17) TF_RND(29) TF_RND(16) TF_RND(24)
  x0 += k1;  x1 += ks2 + 4u;
  TF_RND(13) TF_RND(15) TF_RND(26) TF_RND(6)
  x0 += ks2; x1 += k0 + 5u;
#undef TF_RND
  o0 = x0; o1 = x1;
}

// XLA f32 erfinv (Giles). _rn ops keep XLA's separate roundings.
__device__ __forceinline__ float erfinv32(float x)
{
  float w = -log1pf(-__fmul_rn(x, x));
  float p;
  if (w < 5.0f) {
    w = w - 2.5f;
    p = 2.81022636e-08f;
    p = __fadd_rn( 3.43273939e-07f, __fmul_rn(p, w));
    p = __fadd_rn(-3.5233877e-06f,  __fmul_rn(p, w));
    p = __fadd_rn(-4.39150654e-06f, __fmul_rn(p, w));
    p = __fadd_rn( 0.00021858087f,  __fmul_rn(p, w));
    p = __fadd_rn(-0.00125372503f,  __fmul_rn(p, w));
    p = __fadd_rn(-0.00417768164f,  __fmul_rn(p, w));
    p = __fadd_rn( 0.246640727f,    __fmul_rn(p, w));
    p = __fadd_rn( 1.50140941f,     __fmul_rn(p, w));
  } else {
    w = sqrtf(w) - 3.0f;
    p = -0.000200214257f;
    p = __fadd_rn( 0.000100950558f, __fmul_rn(p, w));
    p = __fadd_rn( 0.00134934322f,  __fmul_rn(p, w));
    p = __fadd_rn(-0.00367342844f,  __fmul_rn(p, w));
    p = __fadd_rn( 0.00573950773f,  __fmul_rn(p, w));
    p = __fadd_rn(-0.0076224613f,   __fmul_rn(p, w));
    p = __fadd_rn( 0.00943887047f,  __fmul_rn(p, w));
    p = __fadd_rn( 1.00167406f,     __fmul_rn(p, w));
    p = __fadd_rn( 2.83297682f,     __fmul_rn(p, w));
  }
  return __fmul_rn(p, x);
}

__device__ __forceinline__ float bits_to_normal(uint32_t bits)
{
  const float lo = -0.99999994f;
  float f = __uint_as_float((bits >> 9) | 0x3F800000u) - 1.0f;
  float u = __fadd_rn(__fmul_rn(f, 2.0f), lo);
  u = fmaxf(lo, u);
  return __fmul_rn(1.41421356f, erfinv32(u));
}

__device__ __forceinline__ float jax_normal_idx(uint32_t k0, uint32_t k1, uint32_t idx)
{
  uint32_t o0, o1;
  tf2x32(k0, k1, 0u, idx, o0, o1);
  return bits_to_normal(o0 ^ o1);
}

__device__ __forceinline__ ushort f2bf(float f)
{
  uint32_t u = __float_as_uint(f);
  u += 0x7fffu + ((u >> 16) & 1u);
  return (ushort)(u >> 16);
}

// Fragment-major packing (verified R7): B-frag (c,ks) = 64 consecutive 16B
// chunks in lane order.
__device__ __forceinline__ int pk128(int row, int col)
{
  return (((row >> 4) * 4 + (col >> 5)) * 64 + ((col >> 3) & 3) * 16 + (row & 15)) * 8
         + (col & 7);
}
__device__ __forceinline__ int pk_w2(int row, int col)
{
  return (col >> 7) * 16384 +
         (((row >> 4) * 4 + ((col >> 5) & 3)) * 64 + ((col >> 3) & 3) * 16 + (row & 15)) * 8
         + (col & 7);
}

// LDS [128][128] ushort buffers, 16B-chunk XOR swizzle (verified R9)
__device__ __forceinline__ int swzc(int row, int chunk)
{
  return row * 128 + ((chunk ^ (row & 15)) << 3);
}
__device__ __forceinline__ int swz(int row, int col)
{
  return row * 128 + ((((col >> 3) ^ (row & 15)) << 3) | (col & 7));
}

// --------------------- fused Bayesian weight sampling ----------------------
#define SA_DECB 262144
#define SA_F1W  264192
#define SA_F1B  329728
#define SA_F2W  330240
#define SA_F2B  395776
#define SA_AW   396032
#define SA_AB   1706752
#define SA_ATW  1716992
#define SA_ATB  1717632
#define SA_TOT  1717637

#define BW_DEC  0
#define BW_F1   262144
#define BW_F2   327680
#define BW_AW   393216
#define BW_TOT  1703936

#define BF_DECB 0
#define BF_F1B  2048
#define BF_F2B  2560
#define BF_AB   2816
#define BF_ATW  13056
#define BF_ATB  13696
#define BF_TOT  13701

__global__ __launch_bounds__(256) void sample_all_kernel(
    const float* __restrict__ dec_wmu, const float* __restrict__ dec_wls,
    const float* __restrict__ dec_bmu, const float* __restrict__ dec_bls,
    const float* __restrict__ f1_wmu,  const float* __restrict__ f1_wls,
    const float* __restrict__ f1_bmu,  const float* __restrict__ f1_bls,
    const float* __restrict__ f2_wmu,  const float* __restrict__ f2_wls,
    const float* __restrict__ f2_bmu,  const float* __restrict__ f2_bls,
    const float* __restrict__ a_wmu,   const float* __restrict__ a_wls,
    const float* __restrict__ a_bmu,   const float* __restrict__ a_bls,
    const float* __restrict__ at_wmu,  const float* __restrict__ at_wls,
    const float* __restrict__ at_bmu,  const float* __restrict__ at_bls,
    ushort* __restrict__ wbf, float* __restrict__ wf32)
{
  const int i = blockIdx.x * 256 + threadIdx.x;
  if (i >= SA_TOT) return;
  const float* mu; const float* ls;
  uint32_t c, idx;
  int bf_dst = -1, f32_dst = -1;
  if (i < SA_DECB) {
    int s = i >> 14, t = i & 16383;
    mu = dec_wmu + i; ls = dec_wls + i;
    c = 2u * s + (s >= 8 ? 4u : 0u); idx = (uint32_t)t;
    bf_dst = BW_DEC + s * 16384 + pk128(t >> 7, t & 127);
  } else if (i < SA_F1W) {
    int t = i - SA_DECB; int s = t >> 7;
    mu = dec_bmu + t; ls = dec_bls + t;
    c = 2u * s + 1u + (s >= 8 ? 4u : 0u); idx = (uint32_t)(t & 127);
    f32_dst = BF_DECB + t;
  } else if (i < SA_F1B) {
    int t = i - SA_F1W; int s = t >> 15, tl = t & 32767;
    mu = f1_wmu + t; ls = f1_wls + t;
    c = 16u + 20u * s; idx = (uint32_t)tl;
    bf_dst = BW_F1 + s * 32768 + pk128(tl >> 7, tl & 127);
  } else if (i < SA_F2W) {
    int t = i - SA_F1B; int s = t >> 8;
    mu = f1_bmu + t; ls = f1_bls + t;
    c = 17u + 20u * s; idx = (uint32_t)(t & 255);
    f32_dst = BF_F1B + t;
  } else if (i < SA_F2B) {
    int t = i - SA_F2W; int s = t >> 15, tl = t & 32767;
    mu = f2_wmu + t; ls = f2_wls + t;
    c = 18u + 20u * s; idx = (uint32_t)tl;
    bf_dst = BW_F2 + s * 32768 + pk_w2(tl >> 8, tl & 255);
  } else if (i < SA_AW) {
    int t = i - SA_F2B; int s = t >> 7;
    mu = f2_bmu + t; ls = f2_bls + t;
    c = 19u + 20u * s; idx = (uint32_t)(t & 127);
    f32_dst = BF_F2B + t;
  } else if (i < SA_AB) {
    int t = i - SA_AW;
    mu = a_wmu + t; ls = a_wls + t; c = 40u; idx = (uint32_t)t;
    int kcomp = t >> 18, rem = t & 262143;
    bf_dst = BW_AW + pk128(kcomp * 2048 + (rem >> 7), rem & 127);
  } else if (i < SA_ATW) {
    int t = i - SA_AB;
    mu = a_bmu + t; ls = a_bls + t; c = 41u; idx = (uint32_t)t;
    f32_dst = BF_AB + t;
  } else if (i < SA_ATB) {
    int t = i - SA_ATW;
    mu = at_wmu + t; ls = at_wls + t; c = 42u; idx = (uint32_t)t;
    f32_dst = BF_ATW + t;
  } else {
    int t = i - SA_ATB;
    mu = at_bmu + t; ls = at_bls + t; c = 43u; idx = (uint32_t)t;
    f32_dst = BF_ATB + t;
  }
  uint32_t k0, k1;
  tf2x32(0u, 42u, 0u, c, k0, k1);
  float v = mu[0] + expf(ls[0]) * jax_normal_idx(k0, k1, idx);
  if (bf_dst >= 0) wbf[bf_dst] = f2bf(v);
  else             wf32[f32_dst] = v;
}

// ------------------- pack em_w / es_w (fp32 -> packed bf16) ----------------
__global__ __launch_bounds__(256) void pack_head_kernel(
    const float* __restrict__ em_w, const float* __restrict__ es_w,
    ushort* __restrict__ EMp, ushort* __restrict__ ESp)
{
  int i = blockIdx.x * 256 + threadIdx.x;
  int kcomp = i >> 18, rem = i & 262143;
  int dst = pk128(kcomp * 2048 + (rem >> 7), rem & 127);
  EMp[dst] = f2bf(em_w[i]);
  ESp[dst] = f2bf(es_w[i]);
}

// ------------------------ decoder megakernel v7 ----------------------------
// 8 waves. GEMMs col-partitioned (wave w: output cols [16w,16w+16), W frags
// in registers from packed global). Attention row-partitioned; XbU doubles
// as the full-width P buffer (Q hoisted to regs first).
__global__ __launch_bounds__(512, 1) void decoder_mega_kernel(
    const int* __restrict__ ev, const int* __restrict__ mask,
    const float* __restrict__ emb,
    const ushort* __restrict__ WBF, const float* __restrict__ WF32,
    const float* __restrict__ lng_all, const float* __restrict__ lnb_all,
    float* __restrict__ Xh, ushort* __restrict__ Hb)
{
  __shared__ ushort XbU[16384];       // x bf16 (swz) / Q park / P buffer
  __shared__ ushort KtU[16384];       // K / O park / H1 cols 128-255
  __shared__ ushort VtU[16384];       // V^T / H1 cols 0-127
  __shared__ ushort IxU[16384];       // inp_x bf16 (swz), static all stages
  __shared__ float  LNs[2688];        // LN scratch: Pp[1152] Pq[1152] Mv[384]

  float* Pp = LNs;                    // [128][9] padded partial sums
  float* Pq = LNs + 1152;             // [128][9] padded partial sumsq
  float2* Mv = (float2*)(LNs + 2304); // [128] (mean, inv)

  const int b = blockIdx.x;
  const int tid = threadIdx.x;
  const int w = tid >> 6, l = tid & 63;
  const int g = l >> 4, r16 = l & 15;
  const int col = 16 * w + r16;       // this lane's GEMM output column
  const f32x4 zero = {0.f, 0.f, 0.f, 0.f};

  auto ldfrag = [&](const ushort* Wp, int fid) -> bf16x8 {
    return *(const bf16x8*)(Wp + ((size_t)(fid << 6) + l) * 8);
  };

  // ---------------- init ----------------
  float xreg[8][4];                   // fp32 master X: row 16m8+4g+r, col
#pragma unroll
  for (int m8 = 0; m8 < 8; ++m8)
#pragma unroll
    for (int r = 0; r < 4; ++r) {
      const int row = 16 * m8 + 4 * g + r;
      const int e = ev[b * NL + row];
      float x = emb[(size_t)e * ND + col];
      xreg[m8][r] = x;
      XbU[swz(row, col)] = f2bf(x);
    }
  {                                   // inp_x -> IxU (row-partitioned)
    const int row = 16 * w + r16;
    const int ea = ev[b * NL + row];
    const int mk = mask[b * NL + row];
    const bool even = (mk & 1) == 0;
    const float fm = (float)mk;
#pragma unroll
    for (int ks = 0; ks < 4; ++ks) {
      float4 x0 = *(const float4*)(emb + (size_t)ea * ND + 32 * ks + 8 * g);
      float4 x1 = *(const float4*)(emb + (size_t)ea * ND + 32 * ks + 8 * g + 4);
      float xs[8] = {x0.x, x0.y, x0.z, x0.w, x1.x, x1.y, x1.z, x1.w};
      bf16x8 v;
#pragma unroll
      for (int e = 0; e < 8; ++e) {
        int d = 32 * ks + 8 * g + e;
        float div = expf((float)d * (float)(-9.210340371976184 / 128.0));
        float ang = fm * div;
        float pe = even ? sinf(ang) : cosf(ang);
        v[e] = (short)f2bf(xs[e] + pe);
      }
      *(bf16x8*)&IxU[swzc(row, 4 * ks + g)] = v;
    }
  }
  __syncthreads();                    // Xb/Ix published

#pragma unroll 1
  for (int st = 0; st < 6; ++st) {
    const int lay = st / 3, m = st - 3 * lay;
    const float* lng = lng_all + (size_t)(lay * 3 + m) * ND;
    const float* lnb = lnb_all + (size_t)(lay * 3 + m) * ND;
    f32x4 acc2[8];
#pragma unroll
    for (int c = 0; c < 8; ++c) acc2[c] = zero;
    float bo_s;

    if (m < 2) {
      // ============== attention stage (m=0 self, m=1 cross) ==============
      const int s0 = lay * 8 + m * 4;
      const ushort* Wq = WBF + BW_DEC + (size_t)(s0 + 0) * 16384;
      const ushort* Wk = WBF + BW_DEC + (size_t)(s0 + 1) * 16384;
      const ushort* Wv = WBF + BW_DEC + (size_t)(s0 + 2) * 16384;
      const ushort* Wo = WBF + BW_DEC + (size_t)(s0 + 3) * 16384;
      const float*  B4 = WF32 + BF_DECB + (size_t)s0 * 128;

      // W frags into registers (per-wave, no sync)
      bf16x8 wk[4], wv[4], wq[4];
#pragma unroll
      for (int ks = 0; ks < 4; ++ks) {
        wk[ks] = ldfrag(Wk, 4 * w + ks);
        wv[ks] = ldfrag(Wv, 4 * w + ks);
        wq[ks] = ldfrag(Wq, 4 * w + ks);
      }
      const ushort* Asrc = (m == 0) ? XbU : IxU;

      // K GEMM -> Kt (cols this wave, all rows)
      {
        f32x4 kacc[8];
#pragma unroll
        for (int c = 0; c < 8; ++c) kacc[c] = zero;
#pragma unroll
        for (int m8 = 0; m8 < 8; ++m8)
#pragma unroll
          for (int ks = 0; ks < 4; ++ks) {
            bf16x8 a = *(const bf16x8*)&Asrc[swzc(16 * m8 + r16, 4 * ks + g)];
            kacc[m8] = MFMA16(a, wk[ks], kacc[m8]);
          }
        float kb = B4[128 + col];
#pragma unroll
        for (int m8 = 0; m8 < 8; ++m8)
#pragma unroll
          for (int r = 0; r < 4; ++r)
            KtU[swz(16 * m8 + 4 * g + r, col)] = f2bf(kacc[m8][r] + kb);
      }
      // V GEMM -> Vt transposed (Vt[d=col][krow])
      {
        f32x4 vacc[8];
#pragma unroll
        for (int c = 0; c < 8; ++c) vacc[c] = zero;
#pragma unroll
        for (int m8 = 0; m8 < 8; ++m8)
#pragma unroll
          for (int ks = 0; ks < 4; ++ks) {
            bf16x8 a = *(const bf16x8*)&Asrc[swzc(16 * m8 + r16, 4 * ks + g)];
            vacc[m8] = MFMA16(a, wv[ks], vacc[m8]);
          }
        float vb = B4[256 + col];
#pragma unroll
        for (int m8 = 0; m8 < 8; ++m8) {
          ushort4 pkv;
          pkv.x = f2bf(vacc[m8][0] + vb); pkv.y = f2bf(vacc[m8][1] + vb);
          pkv.z = f2bf(vacc[m8][2] + vb); pkv.w = f2bf(vacc[m8][3] + vb);
          *(ushort4*)&VtU[swz(col, 16 * m8 + 4 * g)] = pkv;
        }
      }
      // Q GEMM (A always Xb); hold qacc, park after barrier
      f32x4 qacc[8];
#pragma unroll
      for (int c = 0; c < 8; ++c) qacc[c] = zero;
#pragma unroll
      for (int m8 = 0; m8 < 8; ++m8)
#pragma unroll
        for (int ks = 0; ks < 4; ++ks) {
          bf16x8 a = *(const bf16x8*)&XbU[swzc(16 * m8 + r16, 4 * ks + g)];
          qacc[m8] = MFMA16(a, wq[ks], qacc[m8]);
        }
      __syncthreads();                // B1a: all Xb/Ix reads done; K,V published
      {
        float qb = B4[col];
#pragma unroll
        for (int m8 = 0; m8 < 8; ++m8)
#pragma unroll
          for (int r = 0; r < 4; ++r)
            XbU[swz(16 * m8 + 4 * g + r, col)] = f2bf(qacc[m8][r] + qb);
      }
      __syncthreads();                // B1b: Q published

      // ---- attention (row-partitioned: wave w rows [16w,16w+16)) ----
      // hoist Q A-frags -> XbU becomes dead -> full-width P buffer
      bf16x8 qa[4];
#pragma unroll
      for (int h = 0; h < 4; ++h)
        qa[h] = *(const bf16x8*)&XbU[swzc(16 * w + r16, 4 * h + g)];

      const float scale = 0.1767766952966369f;   // 1/sqrt(32)
      f32x4 oacc[4][2];
#pragma unroll
      for (int h = 0; h < 4; ++h) { oacc[h][0] = zero; oacc[h][1] = zero; }
#pragma unroll
      for (int h = 0; h < 4; ++h) {
        f32x4 s[8];
#pragma unroll
        for (int c = 0; c < 8; ++c) {
          bf16x8 kv = *(const bf16x8*)&KtU[swzc(16 * c + r16, 4 * h + g)];
          s[c] = MFMA16(qa[h], kv, zero);
        }
        // softmax row-wise; P -> XbU rows [16w,16w+16) (wave-band-local)
#pragma unroll
        for (int r = 0; r < 4; ++r) {
          float v[8]; float mx = -1e30f;
#pragma unroll
          for (int c = 0; c < 8; ++c) { v[c] = s[c][r] * scale; mx = fmaxf(mx, v[c]); }
#pragma unroll
          for (int o = 1; o < 16; o <<= 1) mx = fmaxf(mx, __shfl_xor(mx, o));
          float sum = 0.f;
#pragma unroll
          for (int c = 0; c < 8; ++c) { v[c] = __expf(v[c] - mx); sum += v[c]; }
#pragma unroll
          for (int o = 1; o < 16; o <<= 1) sum += __shfl_xor(sum, o);
          float inv = 1.0f / sum;
          const int prow = 16 * w + 4 * g + r;
#pragma unroll
          for (int c = 0; c < 8; ++c)
            XbU[swz(prow, 16 * c + r16)] = f2bf(v[c] * inv);
        }
#pragma unroll
        for (int kc = 0; kc < 4; ++kc) {
          bf16x8 pa = *(const bf16x8*)&XbU[swzc(16 * w + r16, 4 * kc + g)];
#pragma unroll
          for (int cc = 0; cc < 2; ++cc) {
            bf16x8 vv = *(const bf16x8*)&VtU[swzc(32 * h + 16 * cc + r16, 4 * kc + g)];
            oacc[h][cc] = MFMA16(pa, vv, oacc[h][cc]);
          }
        }
      }
      __syncthreads();                // B2: attn reads of Kt/Vt done

      // Wo frags (per-wave, covered by O-park writes)
      bf16x8 wo[4];
#pragma unroll
      for (int ks = 0; ks < 4; ++ks) wo[ks] = ldfrag(Wo, 4 * w + ks);
      // O -> Kt park (row band)
#pragma unroll
      for (int h = 0; h < 4; ++h)
#pragma unroll
        for (int cc = 0; cc < 2; ++cc)
#pragma unroll
          for (int r = 0; r < 4; ++r)
            KtU[swz(16 * w + 4 * g + r, 32 * h + 16 * cc + r16)] = f2bf(oacc[h][cc][r]);
      __syncthreads();                // B3: O published

      // out-proj (col-partitioned)
#pragma unroll
      for (int m8 = 0; m8 < 8; ++m8)
#pragma unroll
        for (int ks = 0; ks < 4; ++ks) {
          bf16x8 a = *(const bf16x8*)&KtU[swzc(16 * m8 + r16, 4 * ks + g)];
          acc2[m8] = MFMA16(a, wo[ks], acc2[m8]);
        }
      bo_s = B4[384 + col];
    } else {
      // ========================= FFN stage =========================
      const ushort* W1p = WBF + BW_F1 + (size_t)lay * 32768;
      const ushort* W2p = WBF + BW_F2 + (size_t)lay * 32768;
      const float*  B1 = WF32 + BF_F1B + (size_t)lay * 256;
      const float*  B2 = WF32 + BF_F2B + (size_t)lay * 128;

      // FFN1: wave w owns H1 cols [32w,32w+32) as two 16-col blocks
#pragma unroll
      for (int t = 0; t < 2; ++t) {
        const int cblk = 2 * w + t;
        bf16x8 w1[4];
#pragma unroll
        for (int ks = 0; ks < 4; ++ks) w1[ks] = ldfrag(W1p, 4 * cblk + ks);
        f32x4 a1[8];
#pragma unroll
        for (int c = 0; c < 8; ++c) a1[c] = zero;
#pragma unroll
        for (int m8 = 0; m8 < 8; ++m8)
#pragma unroll
          for (int ks = 0; ks < 4; ++ks) {
            bf16x8 a = *(const bf16x8*)&XbU[swzc(16 * m8 + r16, 4 * ks + g)];
            a1[m8] = MFMA16(a, w1[ks], a1[m8]);
          }
        const int hcol = 32 * w + 16 * t + r16;
        const float b1 = B1[hcol];
        if (cblk < 8) {
#pragma unroll
          for (int m8 = 0; m8 < 8; ++m8)
#pragma unroll
            for (int r = 0; r < 4; ++r)
              VtU[swz(16 * m8 + 4 * g + r, hcol)] = f2bf(fmaxf(a1[m8][r] + b1, 0.f));
        } else {
#pragma unroll
          for (int m8 = 0; m8 < 8; ++m8)
#pragma unroll
            for (int r = 0; r < 4; ++r)
              KtU[swz(16 * m8 + 4 * g + r, hcol - 128)] = f2bf(fmaxf(a1[m8][r] + b1, 0.f));
        }
      }
      // W2 frags (K=256: 8 frags)
      bf16x8 w2[8];
#pragma unroll
      for (int ks8 = 0; ks8 < 8; ++ks8)
        w2[ks8] = ldfrag(W2p + (ks8 >= 4 ? 16384 : 0), 4 * w + (ks8 & 3));
      __syncthreads();                // F1: H1 published

      // FFN2 (col-partitioned, K=256)
#pragma unroll
      for (int m8 = 0; m8 < 8; ++m8)
#pragma unroll
        for (int ks8 = 0; ks8 < 8; ++ks8) {
          bf16x8 a = (ks8 < 4)
            ? *(const bf16x8*)&VtU[swzc(16 * m8 + r16, 4 * ks8 + g)]
            : *(const bf16x8*)&KtU[swzc(16 * m8 + r16, 4 * (ks8 - 4) + g)];
          acc2[m8] = MFMA16(a, w2[ks8], acc2[m8]);
        }
      bo_s = B2[col];
    }

    // -------- epilogue: residual + LayerNorm (cross-wave 2-level) --------
    const float gg = lng[col], lb = lnb[col];
    float xv[8][4];
#pragma unroll
    for (int m8 = 0; m8 < 8; ++m8)
#pragma unroll
      for (int r = 0; r < 4; ++r)
        xv[m8][r] = acc2[m8][r] + bo_s + xreg[m8][r];
#pragma unroll
    for (int m8 = 0; m8 < 8; ++m8)
#pragma unroll
      for (int r = 0; r < 4; ++r) {
        float s = xv[m8][r], q = s * s;
#pragma unroll
        for (int o = 1; o < 16; o <<= 1) { s += __shfl_xor(s, o); q += __shfl_xor(q, o); }
        if (r16 == 0) {
          const int row = 16 * m8 + 4 * g + r;
          Pp[row * 9 + w] = s;
          Pq[row * 9 + w] = q;
        }
      }
    __syncthreads();                  // LN partials published (+P reads done)
    if (tid < 128) {
      float s = 0.f, q = 0.f;
#pragma unroll
      for (int u = 0; u < 8; ++u) { s += Pp[tid * 9 + u]; q += Pq[tid * 9 + u]; }
      float mean = s * (1.0f / 128.0f);
      float var = q * (1.0f / 128.0f) - mean * mean;
      Mv[tid] = float2{mean, 1.0f / sqrtf(var + 1e-5f)};
    }
    __syncthreads();                  // mean/inv published
#pragma unroll
    for (int m8 = 0; m8 < 8; ++m8)
#pragma unroll
      for (int r = 0; r < 4; ++r) {
        const int row = 16 * m8 + 4 * g + r;
        float2 mv = Mv[row];
        float o = (xv[m8][r] - mv.x) * mv.y * gg + lb;
        xreg[m8][r] = o;
        XbU[swz(row, col)] = f2bf(o);
      }
    __syncthreads();                  // Xb published for next stage
  }

  // ---- final: h = x[:,0,:] (row 0 = m8=0, g=0, r=0; cols across waves) ----
  if (g == 0) {
    Xh[(size_t)b * ND + col] = xreg[0][0];
    Hb[(size_t)b * ND + col] = f2bf(xreg[0][0]);
  }
}

// --------------------- fused mixture head kernel ---------------------------
__global__ __launch_bounds__(256) void head_fused_kernel(
    const ushort* __restrict__ Hb,
    const ushort* __restrict__ AWp, const float* __restrict__ ABs,
    const ushort* __restrict__ EMp, const float* __restrict__ em_b,
    const ushort* __restrict__ ESp, const float* __restrict__ es_b,
    float* __restrict__ out, uint32_t k0, uint32_t k1)
{
  const int tt = blockIdx.x;
  const int t0 = tt * 16;
  const int bm = blockIdx.y * 128;
  const int tid = threadIdx.x;
  const int w = tid >> 6, l = tid & 63;
  const int g = l >> 4, r16 = l & 15;
  const f32x4 zero = {0.f, 0.f, 0.f, 0.f};
  const int tl = t0 + r16;

  f32x4 aA[2][5], aE[2][5], aS[2][5];
#pragma unroll
  for (int t = 0; t < 2; ++t)
#pragma unroll
    for (int k = 0; k < 5; ++k) { aA[t][k] = zero; aE[t][k] = zero; aS[t][k] = zero; }

#pragma unroll
  for (int ks = 0; ks < 4; ++ks) {
    bf16x8 a0 = *(const bf16x8*)(Hb + (size_t)(bm + 32 * w + r16) * 128 + 32 * ks + 8 * g);
    bf16x8 a1 = *(const bf16x8*)(Hb + (size_t)(bm + 32 * w + 16 + r16) * 128 + 32 * ks + 8 * g);
#pragma unroll
    for (int k = 0; k < 5; ++k) {
      const size_t CB = (((size_t)(k * 128 + tt) * 4 + ks) * 64 + l) * 8;
      bf16x8 wa = *(const bf16x8*)(AWp + CB);
      aA[0][k] = MFMA16(a0, wa, aA[0][k]);
      aA[1][k] = MFMA16(a1, wa, aA[1][k]);
      bf16x8 we = *(const bf16x8*)(EMp + CB);
      aE[0][k] = MFMA16(a0, we, aE[0][k]);
      aE[1][k] = MFMA16(a1, we, aE[1][k]);
      bf16x8 wsv = *(const bf16x8*)(ESp + CB);
      aS[0][k] = MFMA16(a0, wsv, aS[0][k]);
      aS[1][k] = MFMA16(a1, wsv, aS[1][k]);
    }
  }

  float bA[5], bE[5], bS[5];
#pragma unroll
  for (int k = 0; k < 5; ++k) {
    bA[k] = ABs[k * NT + tl];
    bE[k] = em_b[k * NT + tl];
    bS[k] = es_b[k * NT + tl];
  }

#pragma unroll
  for (int t = 0; t < 2; ++t)
#pragma unroll
    for (int r = 0; r < 4; ++r) {
      const int brow = bm + 32 * w + 16 * t + 4 * g + r;
      float lg[5];
      float mx = -1e30f;
#pragma unroll
      for (int k = 0; k < 5; ++k) { lg[k] = aA[t][k][r] + bA[k]; mx = fmaxf(mx, lg[k]); }
      float se = 0.f;
#pragma unroll
      for (int k = 0; k < 5; ++k) { lg[k] = expf(lg[k] - mx); se += lg[k]; }
      const float inv = 1.0f / se;
      float acc = 0.f;
#pragma unroll
      for (int k = 0; k < 5; ++k) {
        float nz = jax_normal_idx(k0, k1, (uint32_t)((brow * 5 + k) * NT + tl));
        float mean = aE[t][k][r] + bE[k];
        float sd   = expf(aS[t][k][r] + bS[k]);
        acc += (lg[k] * inv) * (mean + sd * nz);
      }
      out[(size_t)brow * NT + tl] = acc;
    }
}

// ------------------------------- time head ---------------------------------
__global__ __launch_bounds__(64) void time_head_kernel(
    const float* __restrict__ Xh, const float* __restrict__ atw,
    const float* __restrict__ atb, const float* __restrict__ tmw,
    const float* __restrict__ tmb, const float* __restrict__ tsw,
    const float* __restrict__ tsb, float* __restrict__ out,
    uint32_t k0, uint32_t k1)
{
  const int b = blockIdx.x;
  const int l = threadIdx.x;
  const float* h = Xh + (size_t)b * ND;
  const float h0 = h[l], h1 = h[l + 64];
  float lg[5], tm[5], tsl[5];
#pragma unroll
  for (int k = 0; k < 5; ++k) {
    float s0 = fmaf(h0, atw[k * ND + l], h1 * atw[k * ND + l + 64]);
    float s1 = fmaf(h0, tmw[k * ND + l], h1 * tmw[k * ND + l + 64]);
    float s2 = fmaf(h0, tsw[k * ND + l], h1 * tsw[k * ND + l + 64]);
#pragma unroll
    for (int o = 32; o; o >>= 1) {
      s0 += __shfl_xor(s0, o);
      s1 += __shfl_xor(s1, o);
      s2 += __shfl_xor(s2, o);
    }
    lg[k] = s0 + atb[k]; tm[k] = s1 + tmb[k]; tsl[k] = s2 + tsb[k];
  }
  if (l == 0) {
    float mx = lg[0];
    for (int k = 1; k < 5; ++k) mx = fmaxf(mx, lg[k]);
    float se = 0.f;
    for (int k = 0; k < 5; ++k) { lg[k] = expf(lg[k] - mx); se += lg[k]; }
    float acc = 0.f;
    for (int k = 0; k < 5; ++k) {
      float nz = jax_normal_idx(k0, k1, (uint32_t)(b * 5 + k));
      acc += (lg[k] / se) * (tm[k] + expf(tsl[k]) * nz);
    }
    out[b] = acc;
  }
}

// ------------------------------ host driver --------------------------------
extern "C" void kernel_launch(void* const* d_in, const int* in_sizes, int n_in,
                              void* d_out, int out_size, void* d_ws, size_t ws_size,
                              hipStream_t stream)
{
  (void)in_sizes; (void)n_in; (void)out_size; (void)ws_size;

  const int*   ev      = (const int*)d_in[0];
  const int*   mask    = (const int*)d_in[2];
  const float* emb     = (const float*)d_in[4];
  const float* dec_wmu = (const float*)d_in[5];
  const float* dec_wls = (const float*)d_in[6];
  const float* dec_bmu = (const float*)d_in[7];
  const float* dec_bls = (const float*)d_in[8];
  const float* f1_wmu  = (const float*)d_in[9];
  const float* f1_wls  = (const float*)d_in[10];
  const float* f1_bmu  = (const float*)d_in[11];
  const float* f1_bls  = (const float*)d_in[12];
  const float* f2_wmu  = (const float*)d_in[13];
  const float* f2_wls  = (const float*)d_in[14];
  const float* f2_bmu  = (const float*)d_in[15];
  const float* f2_bls  = (const float*)d_in[16];
  const float* ln_g    = (const float*)d_in[17];
  const float* ln_b    = (const float*)d_in[18];
  const float* a_wmu   = (const float*)d_in[19];
  const float* a_wls   = (const float*)d_in[20];
  const float* a_bmu   = (const float*)d_in[21];
  const float* a_bls   = (const float*)d_in[22];
  const float* at_wmu  = (const float*)d_in[23];
  const float* at_wls  = (const float*)d_in[24];
  const float* at_bmu  = (const float*)d_in[25];
  const float* at_bls  = (const float*)d_in[26];
  const float* em_w    = (const float*)d_in[27];
  const float* em_b    = (const float*)d_in[28];
  const float* es_w    = (const float*)d_in[29];
  const float* es_b    = (const float*)d_in[30];
  const float* tm_w    = (const float*)d_in[31];
  const float* tm_b    = (const float*)d_in[32];
  const float* ts_w    = (const float*)d_in[33];
  const float* ts_b    = (const float*)d_in[34];

  float* ws = (float*)d_ws;
  ushort* WBF  = (ushort*)ws;
  float*  WF32 = ws + BW_TOT / 2;
  ushort* EMp  = (ushort*)(WF32 + BF_TOT + 3);
  ushort* ESp  = EMp + 5 * NT * ND;
  ushort* Hb   = ESp + 5 * NT * ND;
  float*  Xh   = (float*)(Hb + (size_t)NB * ND);

  uint32_t fk0[46], fk1[46];
  for (uint32_t c = 0; c < 46; ++c) tf2x32(0u, 42u, 0u, c, fk0[c], fk1[c]);

  sample_all_kernel<<<dim3((SA_TOT + 255) / 256), dim3(256), 0, stream>>>(
      dec_wmu, dec_wls, dec_bmu, dec_bls,
      f1_wmu, f1_wls, f1_bmu, f1_bls,
      f2_wmu, f2_wls, f2_bmu, f2_bls,
      a_wmu, a_wls, a_bmu, a_bls,
      at_wmu, at_wls, at_bmu, at_bls, WBF, WF32);

  pack_head_kernel<<<dim3((5 * NT * ND) / 256), dim3(256), 0, stream>>>(
      em_w, es_w, EMp, ESp);

  decoder_mega_kernel<<<dim3(NB), dim3(512), 0, stream>>>(
      ev, mask, emb, WBF, WF32, ln_g, ln_b, Xh, Hb);

  float* out = (float*)d_out;
  head_fused_kernel<<<dim3(NT / 16, 4), dim3(256), 0, stream>>>(
      Hb, WBF + BW_AW, WF32 + BF_AB, EMp, em_b, ESp, es_b,
      out, fk0[44], fk1[44]);
  time_head_kernel<<<dim3(NB), dim3(64), 0, stream>>>(
      Xh, WF32 + BF_ATW, WF32 + BF_ATB, tm_w, tm_b, ts_w, ts_b,
      out + (size_t)NB * NT, fk0[45], fk1[45]);
}

// Round 12
// 307.224 us; speedup vs baseline: 2.0229x; 2.0229x over previous
//
#include <hip/hip_runtime.h>
#include <cstdint>
#include <cstddef>

// ---------------------------------------------------------------------------
// HierarchicalNetwork: 2-layer Bayesian transformer decoder + mixture heads.
// B=512 L=128 D=128 H=4 dk=32 DFF=256 T=2048
// RNG: JAX threefry2x32 partitionable, fold_in(key(42), c) c=0..45 (verified).
// R12: REVERT to R5 (best known: total 309.6us, mega 262us). Five structural
// mega rewrites (R6 global-W, R8 packed-global-W, R9 dbuf+swizzle, R10/R11
// col-partition) all regressed or were neutral -> R5 shape is the local
// optimum. One fix vs R5: the attention h-loop is fully unrolled (R5 had
// #pragma unroll 1 -> oacc/Ps runtime-indexed -> scratch, rule #20).
// ---------------------------------------------------------------------------

#define NB   512
#define NL   128
#define ND   128
#define NH   4
#define NDFF 256
#define NT   2048
#define BL   (NB * NL)

typedef __attribute__((ext_vector_type(8))) short bf16x8;
typedef __attribute__((ext_vector_type(4))) float f32x4;

#define MFMA16(a, b, c) __builtin_amdgcn_mfma_f32_16x16x32_bf16((a), (b), (c), 0, 0, 0)

// ----------------------------- threefry2x32 --------------------------------
__host__ __device__ __forceinline__ void tf2x32(uint32_t k0, uint32_t k1,
                                                uint32_t x0, uint32_t x1,
                                                uint32_t& o0, uint32_t& o1)
{
  const uint32_t ks2 = k0 ^ k1 ^ 0x1BD11BDAu;
  x0 += k0; x1 += k1;
#define TF_RND(r) { x0 += x1; x1 = (x1 << (r)) | (x1 >> (32 - (r))); x1 ^= x0; }
  TF_RND(13) TF_RND(15) TF_RND(26) TF_RND(6)
  x0 += k1;  x1 += ks2 + 1u;
  TF_RND(17) TF_RND(29) TF_RND(16) TF_RND(24)
  x0 += ks2; x1 += k0 + 2u;
  TF_RND(13) TF_RND(15) TF_RND(26) TF_RND(6)
  x0 += k0;  x1 += k1 + 3u;
  TF_RND(17) TF_RND(29) TF_RND(16) TF_RND(24)
  x0 += k1;  x1 += ks2 + 4u;
  TF_RND(13) TF_RND(15) TF_RND(26) TF_RND(6)
  x0 += ks2; x1 += k0 + 5u;
#undef TF_RND
  o0 = x0; o1 = x1;
}

// XLA f32 erfinv (Giles). _rn ops keep XLA's separate roundings.
__device__ __forceinline__ float erfinv32(float x)
{
  float w = -log1pf(-__fmul_rn(x, x));
  float p;
  if (w < 5.0f) {
    w = w - 2.5f;
    p = 2.81022636e-08f;
    p = __fadd_rn( 3.43273939e-07f, __fmul_rn(p, w));
    p = __fadd_rn(-3.5233877e-06f,  __fmul_rn(p, w));
    p = __fadd_rn(-4.39150654e-06f, __fmul_rn(p, w));
    p = __fadd_rn( 0.00021858087f,  __fmul_rn(p, w));
    p = __fadd_rn(-0.00125372503f,  __fmul_rn(p, w));
    p = __fadd_rn(-0.00417768164f,  __fmul_rn(p, w));
    p = __fadd_rn( 0.246640727f,    __fmul_rn(p, w));
    p = __fadd_rn( 1.50140941f,     __fmul_rn(p, w));
  } else {
    w = sqrtf(w) - 3.0f;
    p = -0.000200214257f;
    p = __fadd_rn( 0.000100950558f, __fmul_rn(p, w));
    p = __fadd_rn( 0.00134934322f,  __fmul_rn(p, w));
    p = __fadd_rn(-0.00367342844f,  __fmul_rn(p, w));
    p = __fadd_rn( 0.00573950773f,  __fmul_rn(p, w));
    p = __fadd_rn(-0.0076224613f,   __fmul_rn(p, w));
    p = __fadd_rn( 0.00943887047f,  __fmul_rn(p, w));
    p = __fadd_rn( 1.00167406f,     __fmul_rn(p, w));
    p = __fadd_rn( 2.83297682f,     __fmul_rn(p, w));
  }
  return __fmul_rn(p, x);
}

__device__ __forceinline__ float bits_to_normal(uint32_t bits)
{
  const float lo = -0.99999994f;
  float f = __uint_as_float((bits >> 9) | 0x3F800000u) - 1.0f;
  float u = __fadd_rn(__fmul_rn(f, 2.0f), lo);
  u = fmaxf(lo, u);
  return __fmul_rn(1.41421356f, erfinv32(u));
}

__device__ __forceinline__ float jax_normal_idx(uint32_t k0, uint32_t k1, uint32_t idx)
{
  uint32_t o0, o1;
  tf2x32(k0, k1, 0u, idx, o0, o1);
  return bits_to_normal(o0 ^ o1);
}

__device__ __forceinline__ ushort f2bf(float f)
{
  uint32_t u = __float_as_uint(f);
  u += 0x7fffu + ((u >> 16) & 1u);
  return (ushort)(u >> 16);
}

// --------------------- fused Bayesian weight sampling ----------------------
#define SA_DECB 262144
#define SA_F1W  264192
#define SA_F1B  329728
#define SA_F2W  330240
#define SA_F2B  395776
#define SA_AW   396032
#define SA_AB   1706752
#define SA_ATW  1716992
#define SA_ATB  1717632
#define SA_TOT  1717637

#define BW_DEC  0
#define BW_F1   262144
#define BW_F2   327680
#define BW_AW   393216
#define BW_TOT  1703936

#define BF_DECB 0
#define BF_F1B  2048
#define BF_F2B  2560
#define BF_AB   2816
#define BF_ATW  13056
#define BF_ATB  13696
#define BF_TOT  13701

__global__ __launch_bounds__(256) void sample_all_kernel(
    const float* __restrict__ dec_wmu, const float* __restrict__ dec_wls,
    const float* __restrict__ dec_bmu, const float* __restrict__ dec_bls,
    const float* __restrict__ f1_wmu,  const float* __restrict__ f1_wls,
    const float* __restrict__ f1_bmu,  const float* __restrict__ f1_bls,
    const float* __restrict__ f2_wmu,  const float* __restrict__ f2_wls,
    const float* __restrict__ f2_bmu,  const float* __restrict__ f2_bls,
    const float* __restrict__ a_wmu,   const float* __restrict__ a_wls,
    const float* __restrict__ a_bmu,   const float* __restrict__ a_bls,
    const float* __restrict__ at_wmu,  const float* __restrict__ at_wls,
    const float* __restrict__ at_bmu,  const float* __restrict__ at_bls,
    ushort* __restrict__ wbf, float* __restrict__ wf32)
{
  const int i = blockIdx.x * 256 + threadIdx.x;
  if (i >= SA_TOT) return;
  const float* mu; const float* ls;
  uint32_t c, idx;
  int bf_dst = -1, f32_dst = -1;
  if (i < SA_DECB) {
    int s = i >> 14;
    mu = dec_wmu + i; ls = dec_wls + i;
    c = 2u * s + (s >= 8 ? 4u : 0u); idx = (uint32_t)(i & 16383);
    bf_dst = BW_DEC + i;
  } else if (i < SA_F1W) {
    int t = i - SA_DECB; int s = t >> 7;
    mu = dec_bmu + t; ls = dec_bls + t;
    c = 2u * s + 1u + (s >= 8 ? 4u : 0u); idx = (uint32_t)(t & 127);
    f32_dst = BF_DECB + t;
  } else if (i < SA_F1B) {
    int t = i - SA_F1W; int s = t >> 15;
    mu = f1_wmu + t; ls = f1_wls + t;
    c = 16u + 20u * s; idx = (uint32_t)(t & 32767);
    bf_dst = BW_F1 + t;
  } else if (i < SA_F2W) {
    int t = i - SA_F1B; int s = t >> 8;
    mu = f1_bmu + t; ls = f1_bls + t;
    c = 17u + 20u * s; idx = (uint32_t)(t & 255);
    f32_dst = BF_F1B + t;
  } else if (i < SA_F2B) {
    int t = i - SA_F2W; int s = t >> 15;
    mu = f2_wmu + t; ls = f2_wls + t;
    c = 18u + 20u * s; idx = (uint32_t)(t & 32767);
    bf_dst = BW_F2 + t;
  } else if (i < SA_AW) {
    int t = i - SA_F2B; int s = t >> 7;
    mu = f2_bmu + t; ls = f2_bls + t;
    c = 19u + 20u * s; idx = (uint32_t)(t & 127);
    f32_dst = BF_F2B + t;
  } else if (i < SA_AB) {
    int t = i - SA_AW;
    mu = a_wmu + t; ls = a_wls + t; c = 40u; idx = (uint32_t)t;
    bf_dst = BW_AW + t;
  } else if (i < SA_ATW) {
    int t = i - SA_AB;
    mu = a_bmu + t; ls = a_bls + t; c = 41u; idx = (uint32_t)t;
    f32_dst = BF_AB + t;
  } else if (i < SA_ATB) {
    int t = i - SA_ATW;
    mu = at_wmu + t; ls = at_wls + t; c = 42u; idx = (uint32_t)t;
    f32_dst = BF_ATW + t;
  } else {
    int t = i - SA_ATB;
    mu = at_bmu + t; ls = at_bls + t; c = 43u; idx = (uint32_t)t;
    f32_dst = BF_ATB + t;
  }
  uint32_t k0, k1;
  tf2x32(0u, 42u, 0u, c, k0, k1);
  float v = mu[0] + expf(ls[0]) * jax_normal_idx(k0, k1, idx);
  if (bf_dst >= 0) wbf[bf_dst] = f2bf(v);
  else             wf32[f32_dst] = v;
}

// ------------------------ decoder megakernel -------------------------------
// One block per b, 512 threads = 8 waves; wave w owns rows [16w,16w+16).
// C-frag: row 16w+4g+r, col 16c+r16.  A-frag: row 16w+r16, k-slice 8g.
#define STR 136

__global__ __launch_bounds__(512, 2) void decoder_mega_kernel(
    const int* __restrict__ ev, const int* __restrict__ mask,
    const float* __restrict__ emb,
    const ushort* __restrict__ WBF, const float* __restrict__ WF32,
    const float* __restrict__ lng_all, const float* __restrict__ lnb_all,
    float* __restrict__ Xh, ushort* __restrict__ Hb)
{
  __shared__ ushort WL[128][STR];
  __shared__ ushort Kt[128][STR];
  __shared__ ushort Vt[128][STR];
  __shared__ ushort Xb[128][STR];
  __shared__ ushort Ps[128][72];      // P sliver, parity double-buffered

  const int b = blockIdx.x;
  const int tid = threadIdx.x;
  const int w = tid >> 6, l = tid & 63;
  const int g = l >> 4, r16 = l & 15;
  const f32x4 zero = {0.f, 0.f, 0.f, 0.f};

  // stage a [128][128] bf16 matrix (src row stride srcStride) into dst
  auto stageS = [&](ushort (*dst)[STR], const ushort* src, int srcStride) {
#pragma unroll
    for (int it = 0; it < 4; ++it) {
      int ci = tid + it * 512;
      int row = ci >> 4, q = ci & 15;
      *(bf16x8*)&dst[row][q * 8] = *(const bf16x8*)(src + (size_t)row * srcStride + q * 8);
    }
  };

  // ---------------- init: embedding gather + positional encoding ----------
  float xreg[8][4];                       // fp32 master X, C-frag layout
  {
    int ecr[4];
#pragma unroll
    for (int r = 0; r < 4; ++r) ecr[r] = ev[b * NL + 16 * w + 4 * g + r];
#pragma unroll
    for (int c = 0; c < 8; ++c)
#pragma unroll
      for (int r = 0; r < 4; ++r) {
        float x = emb[(size_t)ecr[r] * ND + 16 * c + r16];
        xreg[c][r] = x;
        Xb[16 * w + 4 * g + r][16 * c + r16] = f2bf(x);
      }
  }
  bf16x8 inpx[4];                         // inp_x = x0 + PE, A-frag layout
  {
    const int row = 16 * w + r16;
    const int ea = ev[b * NL + row];
    const int mk = mask[b * NL + row];
    const bool even = (mk & 1) == 0;
    const float fm = (float)mk;
#pragma unroll
    for (int ks = 0; ks < 4; ++ks) {
      float4 x0 = *(const float4*)(emb + (size_t)ea * ND + 32 * ks + 8 * g);
      float4 x1 = *(const float4*)(emb + (size_t)ea * ND + 32 * ks + 8 * g + 4);
      float xs[8] = {x0.x, x0.y, x0.z, x0.w, x1.x, x1.y, x1.z, x1.w};
      bf16x8 v;
#pragma unroll
      for (int e = 0; e < 8; ++e) {
        int d = 32 * ks + 8 * g + e;
        float div = expf((float)d * (float)(-9.210340371976184 / 128.0));
        float ang = fm * div;
        float pe = even ? sinf(ang) : cosf(ang);
        v[e] = (short)f2bf(xs[e] + pe);
      }
      inpx[ks] = v;
    }
  }

#pragma unroll 1
  for (int st = 0; st < 6; ++st) {
    const int lay = st / 3, m = st - 3 * lay;
    const float* lng = lng_all + (size_t)(lay * 3 + m) * ND;
    const float* lnb = lnb_all + (size_t)(lay * 3 + m) * ND;
    f32x4 acc2[8];
#pragma unroll
    for (int c = 0; c < 8; ++c) acc2[c] = zero;
    float bo[8];

    __syncthreads();                     // prior-stage LDS reads drained
    if (m < 2) {
      // ============== attention stage (m=0 self, m=1 cross) ==============
      const int s0 = lay * 8 + m * 4;
      const ushort* W4 = WBF + BW_DEC + (size_t)s0 * 16384;
      const float*  B4 = WF32 + BF_DECB + (size_t)s0 * 128;

      // ---- Q = X @ Wq^T (held in regs) ----
      stageS(WL, W4, 128);
      __syncthreads();
      f32x4 qacc[8];
#pragma unroll
      for (int c = 0; c < 8; ++c) qacc[c] = zero;
#pragma unroll
      for (int ks = 0; ks < 4; ++ks) {
        bf16x8 a = *(const bf16x8*)&Xb[16 * w + r16][32 * ks + 8 * g];
#pragma unroll
        for (int c = 0; c < 8; ++c) {
          bf16x8 wv = *(const bf16x8*)&WL[16 * c + r16][32 * ks + 8 * g];
          qacc[c] = MFMA16(a, wv, qacc[c]);
        }
      }
      __syncthreads();
      // ---- K -> Kt ----
      stageS(WL, W4 + 16384, 128);
      __syncthreads();
      {
        f32x4 kacc[8];
#pragma unroll
        for (int c = 0; c < 8; ++c) kacc[c] = zero;
#pragma unroll
        for (int ks = 0; ks < 4; ++ks) {
          bf16x8 a = (m == 0) ? *(const bf16x8*)&Xb[16 * w + r16][32 * ks + 8 * g]
                              : inpx[ks];
#pragma unroll
          for (int c = 0; c < 8; ++c) {
            bf16x8 wv = *(const bf16x8*)&WL[16 * c + r16][32 * ks + 8 * g];
            kacc[c] = MFMA16(a, wv, kacc[c]);
          }
        }
#pragma unroll
        for (int c = 0; c < 8; ++c) {
          float kb = B4[128 + 16 * c + r16];
#pragma unroll
          for (int r = 0; r < 4; ++r)
            Kt[16 * w + 4 * g + r][16 * c + r16] = f2bf(kacc[c][r] + kb);
        }
      }
      __syncthreads();
      // ---- V -> Vt (transposed) ----
      stageS(WL, W4 + 2 * 16384, 128);
      __syncthreads();
      {
        f32x4 vacc[8];
#pragma unroll
        for (int c = 0; c < 8; ++c) vacc[c] = zero;
#pragma unroll
        for (int ks = 0; ks < 4; ++ks) {
          bf16x8 a = (m == 0) ? *(const bf16x8*)&Xb[16 * w + r16][32 * ks + 8 * g]
                              : inpx[ks];
#pragma unroll
          for (int c = 0; c < 8; ++c) {
            bf16x8 wv = *(const bf16x8*)&WL[16 * c + r16][32 * ks + 8 * g];
            vacc[c] = MFMA16(a, wv, vacc[c]);
          }
        }
#pragma unroll
        for (int c = 0; c < 8; ++c) {
          float vb = B4[256 + 16 * c + r16];
#pragma unroll
          for (int r = 0; r < 4; ++r)
            Vt[16 * c + r16][16 * w + 4 * g + r] = f2bf(vacc[c][r] + vb);
        }
      }
      __syncthreads();                   // WL(Wv) reads drained
      // ---- Q (+bias) -> WL ----
#pragma unroll
      for (int c = 0; c < 8; ++c) {
        float qb = B4[16 * c + r16];
#pragma unroll
        for (int r = 0; r < 4; ++r)
          WL[16 * w + 4 * g + r][16 * c + r16] = f2bf(qacc[c][r] + qb);
      }
      __syncthreads();                   // Q/Kt/Vt published

      // ---- attention: 4 heads, wave-local rows, P through sliver ----
      const float scale = 0.1767766952966369f;   // 1/sqrt(32)
      f32x4 oacc[4][2];
#pragma unroll
      for (int h = 0; h < 4; ++h) { oacc[h][0] = zero; oacc[h][1] = zero; }
#pragma unroll
      for (int h = 0; h < 4; ++h) {
        bf16x8 qa = *(const bf16x8*)&WL[16 * w + r16][32 * h + 8 * g];
        f32x4 s[8];
#pragma unroll
        for (int c = 0; c < 8; ++c) {
          bf16x8 kv = *(const bf16x8*)&Kt[16 * c + r16][32 * h + 8 * g];
          s[c] = MFMA16(qa, kv, zero);
        }
        float pv[4][8];
#pragma unroll
        for (int r = 0; r < 4; ++r) {
          float v[8]; float mx = -1e30f;
#pragma unroll
          for (int c = 0; c < 8; ++c) { v[c] = s[c][r] * scale; mx = fmaxf(mx, v[c]); }
#pragma unroll
          for (int o = 1; o < 16; o <<= 1) mx = fmaxf(mx, __shfl_xor(mx, o));
          float sum = 0.f;
#pragma unroll
          for (int c = 0; c < 8; ++c) { v[c] = __expf(v[c] - mx); sum += v[c]; }
#pragma unroll
          for (int o = 1; o < 16; o <<= 1) sum += __shfl_xor(sum, o);
          float inv = 1.0f / sum;
#pragma unroll
          for (int c = 0; c < 8; ++c) pv[r][c] = v[c] * inv;
        }
#pragma unroll
        for (int kc = 0; kc < 4; ++kc) {
          const int po = (kc & 1) * 32;
#pragma unroll
          for (int c2 = 0; c2 < 2; ++c2)
#pragma unroll
            for (int r = 0; r < 4; ++r)
              Ps[16 * w + 4 * g + r][po + 16 * c2 + r16] = f2bf(pv[r][2 * kc + c2]);
          bf16x8 pa = *(const bf16x8*)&Ps[16 * w + r16][po + 8 * g];
#pragma unroll
          for (int cc = 0; cc < 2; ++cc) {
            bf16x8 vv = *(const bf16x8*)&Vt[32 * h + 16 * cc + r16][32 * kc + 8 * g];
            oacc[h][cc] = MFMA16(pa, vv, oacc[h][cc]);
          }
        }
      }
      __syncthreads();                   // Kt/Vt/WL cross-wave reads drained
      // ---- O -> Kt; Wo -> WL; out-proj ----
#pragma unroll
      for (int h = 0; h < 4; ++h)
#pragma unroll
        for (int cc = 0; cc < 2; ++cc)
#pragma unroll
          for (int r = 0; r < 4; ++r)
            Kt[16 * w + 4 * g + r][32 * h + 16 * cc + r16] = f2bf(oacc[h][cc][r]);
      stageS(WL, W4 + 3 * 16384, 128);
      __syncthreads();
#pragma unroll
      for (int ks = 0; ks < 4; ++ks) {
        bf16x8 a = *(const bf16x8*)&Kt[16 * w + r16][32 * ks + 8 * g];
#pragma unroll
        for (int c = 0; c < 8; ++c) {
          bf16x8 wv = *(const bf16x8*)&WL[16 * c + r16][32 * ks + 8 * g];
          acc2[c] = MFMA16(a, wv, acc2[c]);
        }
      }
#pragma unroll
      for (int c = 0; c < 8; ++c) bo[c] = B4[384 + 16 * c + r16];
    } else {
      // ========================= FFN stage =========================
      const ushort* W1 = WBF + BW_F1 + (size_t)lay * 32768;
      const ushort* W2 = WBF + BW_F2 + (size_t)lay * 32768;
      const float*  B1 = WF32 + BF_F1B + (size_t)lay * 256;
      const float*  B2 = WF32 + BF_F2B + (size_t)lay * 128;
      stageS(WL, W1, 128);
      stageS(Kt, W1 + (size_t)128 * 128, 128);
      __syncthreads();
      f32x4 acc1[16];
#pragma unroll
      for (int c = 0; c < 16; ++c) acc1[c] = zero;
#pragma unroll
      for (int ks = 0; ks < 4; ++ks) {
        bf16x8 a = *(const bf16x8*)&Xb[16 * w + r16][32 * ks + 8 * g];
#pragma unroll
        for (int c = 0; c < 8; ++c) {
          bf16x8 w1v = *(const bf16x8*)&WL[16 * c + r16][32 * ks + 8 * g];
          acc1[c] = MFMA16(a, w1v, acc1[c]);
          bf16x8 w2v = *(const bf16x8*)&Kt[16 * c + r16][32 * ks + 8 * g];
          acc1[8 + c] = MFMA16(a, w2v, acc1[8 + c]);
        }
      }
      __syncthreads();                   // W1 reads drained
      // H1 = relu(+bias) -> WL (cols 0-127) / Kt (cols 128-255)
#pragma unroll
      for (int c = 0; c < 16; ++c) {
        float bb = B1[16 * c + r16];
#pragma unroll
        for (int r = 0; r < 4; ++r) {
          float o = fmaxf(acc1[c][r] + bb, 0.f);
          if (c < 8) WL[16 * w + 4 * g + r][16 * c + r16] = f2bf(o);
          else       Kt[16 * w + 4 * g + r][16 * (c - 8) + r16] = f2bf(o);
        }
      }
      stageS(Vt, W2, 256);               // W2 k-cols 0-127
      __syncthreads();
#pragma unroll
      for (int ks = 0; ks < 4; ++ks) {
        bf16x8 a = *(const bf16x8*)&WL[16 * w + r16][32 * ks + 8 * g];
#pragma unroll
        for (int c = 0; c < 8; ++c) {
          bf16x8 wv = *(const bf16x8*)&Vt[16 * c + r16][32 * ks + 8 * g];
          acc2[c] = MFMA16(a, wv, acc2[c]);
        }
      }
      __syncthreads();                   // Vt(W2a) reads drained
      stageS(Vt, W2 + 128, 256);         // W2 k-cols 128-255
      __syncthreads();
#pragma unroll
      for (int ks = 0; ks < 4; ++ks) {
        bf16x8 a = *(const bf16x8*)&Kt[16 * w + r16][32 * ks + 8 * g];
#pragma unroll
        for (int c = 0; c < 8; ++c) {
          bf16x8 wv = *(const bf16x8*)&Vt[16 * c + r16][32 * ks + 8 * g];
          acc2[c] = MFMA16(a, wv, acc2[c]);
        }
      }
#pragma unroll
      for (int c = 0; c < 8; ++c) bo[c] = B2[16 * c + r16];
    }

    // ---------------- shared epilogue: residual + LayerNorm ----------------
    float gg[8], lb[8];
#pragma unroll
    for (int c = 0; c < 8; ++c) { gg[c] = lng[16 * c + r16]; lb[c] = lnb[16 * c + r16]; }
#pragma unroll
    for (int r = 0; r < 4; ++r) {
      float xv[8];
#pragma unroll
      for (int c = 0; c < 8; ++c) xv[c] = acc2[c][r] + bo[c] + xreg[c][r];
      float s = 0.f;
#pragma unroll
      for (int c = 0; c < 8; ++c) s += xv[c];
#pragma unroll
      for (int o = 1; o < 16; o <<= 1) s += __shfl_xor(s, o);
      float mean = s * (1.0f / 128.0f);
      float q = 0.f;
#pragma unroll
      for (int c = 0; c < 8; ++c) { float d = xv[c] - mean; q += d * d; }
#pragma unroll
      for (int o = 1; o < 16; o <<= 1) q += __shfl_xor(q, o);
      float inv = 1.0f / sqrtf(q * (1.0f / 128.0f) + 1e-5f);
#pragma unroll
      for (int c = 0; c < 8; ++c) {
        float o = (xv[c] - mean) * inv * gg[c] + lb[c];
        xreg[c][r] = o;
        Xb[16 * w + 4 * g + r][16 * c + r16] = f2bf(o);
      }
    }
  }

  // ---- final: h = x[:,0,:] (row 0) ----
  if (w == 0 && g == 0) {
#pragma unroll
    for (int c = 0; c < 8; ++c) {
      Xh[(size_t)b * ND + 16 * c + r16] = xreg[c][0];
      Hb[(size_t)b * ND + 16 * c + r16] = f2bf(xreg[c][0]);
    }
  }
}

// ------------------------------ head GEMM ----------------------------------
template<int WFP32>
__global__ __launch_bounds__(256) void head_gemm(
    const ushort* __restrict__ A,
    const ushort* __restrict__ Wb16, const float* __restrict__ Wf32,
    const float* __restrict__ bias, float* __restrict__ C, int ldc)
{
  __shared__ char smem[128 * 132 * 4];
  ushort (*Wl)[STR] = (ushort(*)[STR])smem;
  float  (*Cl)[132] = (float(*)[132])smem;

  const int tid = threadIdx.x;
  const int bn = blockIdx.x * 128;
  const int bm = blockIdx.y * 128;
  const int w = tid >> 6, l = tid & 63;
  const int r16 = l & 15, g = l >> 4;
  const f32x4 zero = {0.f, 0.f, 0.f, 0.f};

#pragma unroll
  for (int it = 0; it < 8; ++it) {
    int ci = tid + it * 256;
    int row = ci >> 4, q = ci & 15;
    if (WFP32) {
      float4 v0 = *(const float4*)(Wf32 + (size_t)(bn + row) * 128 + q * 8);
      float4 v1 = *(const float4*)(Wf32 + (size_t)(bn + row) * 128 + q * 8 + 4);
      bf16x8 o;
      o[0] = f2bf(v0.x); o[1] = f2bf(v0.y); o[2] = f2bf(v0.z); o[3] = f2bf(v0.w);
      o[4] = f2bf(v1.x); o[5] = f2bf(v1.y); o[6] = f2bf(v1.z); o[7] = f2bf(v1.w);
      *(bf16x8*)&Wl[row][q * 8] = o;
    } else {
      *(bf16x8*)&Wl[row][q * 8] =
          *(const bf16x8*)(Wb16 + (size_t)(bn + row) * 128 + q * 8);
    }
  }
  __syncthreads();

  f32x4 acc[2][8];
#pragma unroll
  for (int t = 0; t < 2; ++t)
#pragma unroll
    for (int c = 0; c < 8; ++c) acc[t][c] = zero;
#pragma unroll
  for (int ks = 0; ks < 4; ++ks) {
    bf16x8 a[2];
#pragma unroll
    for (int t = 0; t < 2; ++t)
      a[t] = *(const bf16x8*)(A + (size_t)(bm + 32 * w + 16 * t + r16) * 128
                              + 32 * ks + 8 * g);
    bf16x8 wv[8];
#pragma unroll
    for (int c = 0; c < 8; ++c)
      wv[c] = *(const bf16x8*)&Wl[16 * c + r16][32 * ks + 8 * g];
#pragma unroll
    for (int t = 0; t < 2; ++t)
#pragma unroll
      for (int c = 0; c < 8; ++c)
        acc[t][c] = MFMA16(a[t], wv[c], acc[t][c]);
  }

  float bcol[8];
#pragma unroll
  for (int c = 0; c < 8; ++c) bcol[c] = bias[bn + 16 * c + r16];
  __syncthreads();

#pragma unroll
  for (int t = 0; t < 2; ++t)
#pragma unroll
    for (int c = 0; c < 8; ++c)
#pragma unroll
      for (int r = 0; r < 4; ++r)
        Cl[32 * w + 16 * t + 4 * g + r][16 * c + r16] = acc[t][c][r] + bcol[c];
  __syncthreads();
#pragma unroll
  for (int i = 0; i < 16; ++i) {
    int ci = l + 64 * i;
    int row = 32 * w + (ci >> 5), q = ci & 31;
    float4 v = *(const float4*)&Cl[row][4 * q];
    *(float4*)(C + (size_t)(bm + row) * ldc + bn + 4 * q) = v;
  }
}

// ------------------------------ event head ---------------------------------
__global__ __launch_bounds__(256) void event_head_kernel(
    const float* __restrict__ LA, const float* __restrict__ MB,
    const float* __restrict__ SB, float* __restrict__ out,
    uint32_t k0, uint32_t k1)
{
  int i = blockIdx.x * 256 + threadIdx.x;
  if (i >= NB * NT) return;
  int b = i >> 11, t = i & (NT - 1);
  size_t base = (size_t)b * (5 * NT) + t;
  float lg[5];
  float mx = -1e30f;
#pragma unroll
  for (int k = 0; k < 5; ++k) { lg[k] = LA[base + (size_t)k * NT]; mx = fmaxf(mx, lg[k]); }
  float se = 0.f;
#pragma unroll
  for (int k = 0; k < 5; ++k) { lg[k] = expf(lg[k] - mx); se += lg[k]; }
  float inv = 1.0f / se;
  float acc = 0.f;
#pragma unroll
  for (int k = 0; k < 5; ++k) {
    float nz = jax_normal_idx(k0, k1, (uint32_t)((b * 5 + k) * NT + t));
    float mean = MB[base + (size_t)k * NT];
    float sd   = expf(SB[base + (size_t)k * NT]);
    acc += (lg[k] * inv) * (mean + sd * nz);
  }
  out[i] = acc;
}

// ------------------------------- time head ---------------------------------
__global__ __launch_bounds__(64) void time_head_kernel(
    const float* __restrict__ Xh, const float* __restrict__ atw,
    const float* __restrict__ atb, const float* __restrict__ tmw,
    const float* __restrict__ tmb, const float* __restrict__ tsw,
    const float* __restrict__ tsb, float* __restrict__ out,
    uint32_t k0, uint32_t k1)
{
  const int b = blockIdx.x;
  const int l = threadIdx.x;
  const float* h = Xh + (size_t)b * ND;
  const float h0 = h[l], h1 = h[l + 64];
  float lg[5], tm[5], tsl[5];
#pragma unroll
  for (int k = 0; k < 5; ++k) {
    float s0 = fmaf(h0, atw[k * ND + l], h1 * atw[k * ND + l + 64]);
    float s1 = fmaf(h0, tmw[k * ND + l], h1 * tmw[k * ND + l + 64]);
    float s2 = fmaf(h0, tsw[k * ND + l], h1 * tsw[k * ND + l + 64]);
#pragma unroll
    for (int o = 32; o; o >>= 1) {
      s0 += __shfl_xor(s0, o);
      s1 += __shfl_xor(s1, o);
      s2 += __shfl_xor(s2, o);
    }
    lg[k] = s0 + atb[k]; tm[k] = s1 + tmb[k]; tsl[k] = s2 + tsb[k];
  }
  if (l == 0) {
    float mx = lg[0];
    for (int k = 1; k < 5; ++k) mx = fmaxf(mx, lg[k]);
    float se = 0.f;
    for (int k = 0; k < 5; ++k) { lg[k] = expf(lg[k] - mx); se += lg[k]; }
    float acc = 0.f;
    for (int k = 0; k < 5; ++k) {
      float nz = jax_normal_idx(k0, k1, (uint32_t)(b * 5 + k));
      acc += (lg[k] / se) * (tm[k] + expf(tsl[k]) * nz);
    }
    out[b] = acc;
  }
}

// ------------------------------ host driver --------------------------------
extern "C" void kernel_launch(void* const* d_in, const int* in_sizes, int n_in,
                              void* d_out, int out_size, void* d_ws, size_t ws_size,
                              hipStream_t stream)
{
  (void)in_sizes; (void)n_in; (void)out_size; (void)ws_size;

  const int*   ev      = (const int*)d_in[0];
  const int*   mask    = (const int*)d_in[2];
  const float* emb     = (const float*)d_in[4];
  const float* dec_wmu = (const float*)d_in[5];
  const float* dec_wls = (const float*)d_in[6];
  const float* dec_bmu = (const float*)d_in[7];
  const float* dec_bls = (const float*)d_in[8];
  const float* f1_wmu  = (const float*)d_in[9];
  const float* f1_wls  = (const float*)d_in[10];
  const float* f1_bmu  = (const float*)d_in[11];
  const float* f1_bls  = (const float*)d_in[12];
  const float* f2_wmu  = (const float*)d_in[13];
  const float* f2_wls  = (const float*)d_in[14];
  const float* f2_bmu  = (const float*)d_in[15];
  const float* f2_bls  = (const float*)d_in[16];
  const float* ln_g    = (const float*)d_in[17];
  const float* ln_b    = (const float*)d_in[18];
  const float* a_wmu   = (const float*)d_in[19];
  const float* a_wls   = (const float*)d_in[20];
  const float* a_bmu   = (const float*)d_in[21];
  const float* a_bls   = (const float*)d_in[22];
  const float* at_wmu  = (const float*)d_in[23];
  const float* at_wls  = (const float*)d_in[24];
  const float* at_bmu  = (const float*)d_in[25];
  const float* at_bls  = (const float*)d_in[26];
  const float* em_w    = (const float*)d_in[27];
  const float* em_b    = (const float*)d_in[28];
  const float* es_w    = (const float*)d_in[29];
  const float* es_b    = (const float*)d_in[30];
  const float* tm_w    = (const float*)d_in[31];
  const float* tm_b    = (const float*)d_in[32];
  const float* ts_w    = (const float*)d_in[33];
  const float* ts_b    = (const float*)d_in[34];

  float* ws = (float*)d_ws;
  const size_t HN = (size_t)NB * 5 * NT;     // 5,242,880
  float*  LA   = ws;
  float*  MBo  = LA + HN;
  float*  SBo  = MBo + HN;
  ushort* WBF  = (ushort*)(SBo + HN);        // sampled weights bf16
  float*  WF32 = SBo + HN + BW_TOT / 2;      // sampled biases fp32
  ushort* Hb   = (ushort*)(WF32 + BF_TOT + 3);   // 16B-aligned bf16 h
  float*  Xh   = (float*)(Hb + (size_t)NB * ND); // fp32 h

  uint32_t fk0[46], fk1[46];
  for (uint32_t c = 0; c < 46; ++c) tf2x32(0u, 42u, 0u, c, fk0[c], fk1[c]);

  sample_all_kernel<<<dim3((SA_TOT + 255) / 256), dim3(256), 0, stream>>>(
      dec_wmu, dec_wls, dec_bmu, dec_bls,
      f1_wmu, f1_wls, f1_bmu, f1_bls,
      f2_wmu, f2_wls, f2_bmu, f2_bls,
      a_wmu, a_wls, a_bmu, a_bls,
      at_wmu, at_wls, at_bmu, at_bls, WBF, WF32);

  decoder_mega_kernel<<<dim3(NB), dim3(512), 0, stream>>>(
      ev, mask, emb, WBF, WF32, ln_g, ln_b, Xh, Hb);

  head_gemm<0><<<dim3(80, 4), dim3(256), 0, stream>>>(
      Hb, WBF + BW_AW, nullptr, WF32 + BF_AB, LA, 5 * NT);
  head_gemm<1><<<dim3(80, 4), dim3(256), 0, stream>>>(
      Hb, nullptr, em_w, em_b, MBo, 5 * NT);
  head_gemm<1><<<dim3(80, 4), dim3(256), 0, stream>>>(
      Hb, nullptr, es_w, es_b, SBo, 5 * NT);

  float* out = (float*)d_out;
  event_head_kernel<<<dim3((NB * NT) / 256), dim3(256), 0, stream>>>(
      LA, MBo, SBo, out, fk0[44], fk1[44]);
  time_head_kernel<<<dim3(NB), dim3(64), 0, stream>>>(
      Xh, WF32 + BF_ATW, WF32 + BF_ATB, tm_w, tm_b, ts_w, ts_b,
      out + (size_t)NB * NT, fk0[45], fk1[45]);
}